// Round 7
// baseline (984.079 us; speedup 1.0000x reference)
//
#include <hip/hip_runtime.h>
#include <hip/hip_bf16.h>
#include <hip/hip_cooperative_groups.h>

namespace cg = cooperative_groups;

// GraphSAGE forward. R6: launch-count reduction via cooperative kernels.
// 5 dispatches: K1(prep+CSR, coop) -> gemm1 -> gather1 -> gemm2 -> K2(gather2+pool+head, coop).
// Per layer: Y = H_in @ [Wn | Ws] (bf16, Mpad x 512), then fused gather:
//   h_out[v] = bf16( relu( (sum_e Yn[eidx[e]]) / max(deg,1) + Ys[v] + b ) )

#define HID 256
#define NCOL 512

typedef __bf16 bf16x8 __attribute__((ext_vector_type(8)));
typedef float floatx4 __attribute__((ext_vector_type(4)));
typedef unsigned int u32;
typedef const u32 __attribute__((address_space(1)))* gp_t;
typedef u32 __attribute__((address_space(3)))* lp_t;

__device__ __forceinline__ ushort f2bf(float f) {   // round-to-nearest-even
    unsigned u = __float_as_uint(f);
    u += 0x7fffu + ((u >> 16) & 1u);
    return (ushort)(u >> 16);
}
__device__ __forceinline__ float bf2f(ushort b) {
    return __uint_as_float(((unsigned)b) << 16);
}

// ================= K1: prep + CSR build (cooperative) =================
// A: zero degi/pooled | cvt x->bf16 | packT W1 | packT W2
// B: degree histogram ; C: chunk sums ; D: 1-wave scan ; E: rescan->off,cursor ; F: fill
__global__ __launch_bounds__(256) void prep_csr_kernel(
        const float* __restrict__ x, ushort* __restrict__ xb, int n4,
        const float* __restrict__ W1n, const float* __restrict__ W1s, ushort* __restrict__ w1t, int K1,
        const float* __restrict__ W2n, const float* __restrict__ W2s, ushort* __restrict__ w2t, int K2,
        const int* __restrict__ src, const int* __restrict__ dst,
        int* __restrict__ degi, int* __restrict__ partials,
        int* __restrict__ off, int* __restrict__ cursor, int* __restrict__ eidx,
        float* __restrict__ pooled_zero, int n_zero_pool,
        int n_nodes, int n_edges, int nb) {
    cg::grid_group grid = cg::this_grid();
    int t = threadIdx.x, bid = blockIdx.x;
    int gid = bid * 256 + t;
    int stride = gridDim.x * 256;
    int lane = t & 63, w = t >> 6;
    __shared__ int wsum[4];

    // ---- phase A: zero + cvt + packT (disjoint outputs)
    for (int i = gid; i < n_nodes; i += stride) degi[i] = 0;
    for (int i = gid; i < n_zero_pool; i += stride) pooled_zero[i] = 0.f;
    for (int i = gid; i < n4; i += stride) {
        float4 v = ((const float4*)x)[i];
        ushort4 o;
        o.x = f2bf(v.x); o.y = f2bf(v.y); o.z = f2bf(v.z); o.w = f2bf(v.w);
        ((ushort4*)xb)[i] = o;
    }
    for (int i = gid; i < NCOL * K1; i += stride) {
        int n = i / K1, k = i - n * K1;
        float v = (n < HID) ? W1n[k * HID + n] : W1s[k * HID + (n - HID)];
        w1t[i] = f2bf(v);
    }
    for (int i = gid; i < NCOL * K2; i += stride) {
        int n = i / K2, k = i - n * K2;
        float v = (n < HID) ? W2n[k * HID + n] : W2s[k * HID + (n - HID)];
        w2t[i] = f2bf(v);
    }
    grid.sync();

    // ---- phase B: histogram
    for (int e = gid; e < n_edges; e += stride) atomicAdd(&degi[dst[e]], 1);
    grid.sync();

    // ---- phase C: per-256-chunk sums
    for (int c = bid; c < nb; c += gridDim.x) {
        int i = c * 256 + t;
        int v = (i < n_nodes) ? degi[i] : 0;
#pragma unroll
        for (int d = 1; d < 64; d <<= 1) v += __shfl_xor(v, d, 64);
        if (lane == 0) wsum[w] = v;
        __syncthreads();
        if (t == 0) partials[c] = wsum[0] + wsum[1] + wsum[2] + wsum[3];
        __syncthreads();
    }
    grid.sync();

    // ---- phase D: 1-wave exclusive scan of partials (block 0)
    if (bid == 0 && t < 64) {
        int carry = 0;
        for (int base = 0; base < nb; base += 256) {
            int i0 = base + lane * 4;
            int v0 = (i0 + 0 < nb) ? partials[i0 + 0] : 0;
            int v1 = (i0 + 1 < nb) ? partials[i0 + 1] : 0;
            int v2 = (i0 + 2 < nb) ? partials[i0 + 2] : 0;
            int v3 = (i0 + 3 < nb) ? partials[i0 + 3] : 0;
            int local = v0 + v1 + v2 + v3;
            int s = local;
#pragma unroll
            for (int d = 1; d < 64; d <<= 1) {
                int u = __shfl_up(s, d, 64);
                if (lane >= d) s += u;
            }
            int excl = carry + s - local;
            if (i0 + 0 < nb) partials[i0 + 0] = excl;
            excl += v0;
            if (i0 + 1 < nb) partials[i0 + 1] = excl;
            excl += v1;
            if (i0 + 2 < nb) partials[i0 + 2] = excl;
            excl += v2;
            if (i0 + 3 < nb) partials[i0 + 3] = excl;
            carry += __shfl(s, 63, 64);
        }
        if (lane == 0) off[n_nodes] = carry;
    }
    grid.sync();

    // ---- phase E: per-chunk rescan + chunk offset -> off, cursor
    for (int c = bid; c < nb; c += gridDim.x) {
        int i = c * 256 + t;
        int v = (i < n_nodes) ? degi[i] : 0;
        int s = v;
#pragma unroll
        for (int d = 1; d < 64; d <<= 1) {
            int u = __shfl_up(s, d, 64);
            if (lane >= d) s += u;
        }
        if (lane == 63) wsum[w] = s;
        __syncthreads();
        int woff = 0;
        for (int k = 0; k < w; ++k) woff += wsum[k];
        int excl = partials[c] + woff + s - v;
        if (i < n_nodes) { off[i] = excl; cursor[i] = excl; }
        __syncthreads();
    }
    grid.sync();

    // ---- phase F: fill eidx
    for (int e = gid; e < n_edges; e += stride) {
        int p = atomicAdd(&cursor[dst[e]], 1);
        eidx[p] = src[e];
    }
}

// ================= bf16 MFMA GEMM (as R5: 64x128 tile, dbuf, 3 blocks/CU) ========
__global__ __launch_bounds__(256) void gemm_mfma(const ushort* __restrict__ A,
                                                 const ushort* __restrict__ BT,
                                                 ushort* __restrict__ Y, int K) {
    __shared__ ushort As[2][64 * 64];
    __shared__ ushort Bs[2][128 * 64];
    int tid = threadIdx.x;
    int w = tid >> 6, lane = tid & 63;
    int quad = lane >> 4, r16 = lane & 15;
    int m0 = blockIdx.y * 64, n0 = blockIdx.x * 128;
    int wm = (w >> 1) * 32, wn = (w & 1) * 64;

    int arow[2], agu[2], brow[4], bgu[4];
#pragma unroll
    for (int rr = 0; rr < 2; ++rr) {
        int idx = rr * 256 + tid;
        arow[rr] = idx >> 3;
        agu[rr] = (idx & 7) ^ (arow[rr] & 7);
    }
#pragma unroll
    for (int rr = 0; rr < 4; ++rr) {
        int idx = rr * 256 + tid;
        brow[rr] = idx >> 3;
        bgu[rr] = (idx & 7) ^ (brow[rr] & 7);
    }

    auto stage = [&](int buf, int k0) {
#pragma unroll
        for (int rr = 0; rr < 2; ++rr) {
            const ushort* ga = A + (size_t)(m0 + arow[rr]) * K + k0 + agu[rr] * 8;
            ushort* la = As[buf] + (size_t)(rr * 256 + w * 64) * 8;
            __builtin_amdgcn_global_load_lds((gp_t)(const void*)ga, (lp_t)(void*)la, 16, 0, 0);
        }
#pragma unroll
        for (int rr = 0; rr < 4; ++rr) {
            const ushort* gb = BT + (size_t)(n0 + brow[rr]) * K + k0 + bgu[rr] * 8;
            ushort* lb = Bs[buf] + (size_t)(rr * 256 + w * 64) * 8;
            __builtin_amdgcn_global_load_lds((gp_t)(const void*)gb, (lp_t)(void*)lb, 16, 0, 0);
        }
    };

    floatx4 acc[2][4];
#pragma unroll
    for (int i = 0; i < 2; ++i)
#pragma unroll
        for (int j = 0; j < 4; ++j) acc[i][j] = (floatx4){0.f, 0.f, 0.f, 0.f};

    const int nk = K >> 6;
    stage(0, 0);
    for (int t = 0; t < nk; ++t) {
        int cb = t & 1;
        __syncthreads();
        if (t + 1 < nk) stage(cb ^ 1, (t + 1) << 6);
        const ushort* Ab = As[cb];
        const ushort* Bb = Bs[cb];
#pragma unroll
        for (int s = 0; s < 2; ++s) {
            bf16x8 a[2], b[4];
#pragma unroll
            for (int i = 0; i < 2; ++i) {
                int row = wm + i * 16 + r16;
                int au = (s * 4 + quad) ^ (row & 7);
                a[i] = *(const bf16x8*)(Ab + row * 64 + au * 8);
            }
#pragma unroll
            for (int j = 0; j < 4; ++j) {
                int row = wn + j * 16 + r16;
                int bu = (s * 4 + quad) ^ (row & 7);
                b[j] = *(const bf16x8*)(Bb + row * 64 + bu * 8);
            }
#pragma unroll
            for (int i = 0; i < 2; ++i)
#pragma unroll
                for (int j = 0; j < 4; ++j)
                    acc[i][j] = __builtin_amdgcn_mfma_f32_16x16x32_bf16(a[i], b[j], acc[i][j], 0, 0, 0);
        }
    }
#pragma unroll
    for (int i = 0; i < 2; ++i)
#pragma unroll
        for (int j = 0; j < 4; ++j) {
            int col = n0 + wn + j * 16 + r16;
#pragma unroll
            for (int rg = 0; rg < 4; ++rg) {
                int row = m0 + wm + i * 16 + quad * 4 + rg;
                Y[(size_t)row * NCOL + col] = f2bf(acc[i][j][rg]);
            }
        }
}

// ================= gather body (shared by standalone + coop tail) ==============
__device__ __forceinline__ void gather_body(const ushort* __restrict__ Y,
                                            const int* __restrict__ off,
                                            const int* __restrict__ eidx,
                                            const float* __restrict__ bias,
                                            ushort* __restrict__ h, int n_nodes,
                                            int wave0, int wstride) {
    int lane = threadIdx.x & 63;
    int q4 = lane << 2;
    for (int v = wave0; v < n_nodes; v += wstride) {
        int e0 = off[v], e1 = off[v + 1];
        ushort4 sv = *(const ushort4*)(Y + (size_t)v * NCOL + HID + q4);
        float4 b = *(const float4*)(bias + q4);
        float4 a0 = make_float4(0.f, 0.f, 0.f, 0.f), a1 = a0, a2 = a0, a3 = a0;
        int e = e0;
        for (; e + 3 < e1; e += 4) {
            int s0 = eidx[e], s1 = eidx[e + 1], s2 = eidx[e + 2], s3 = eidx[e + 3];
            ushort4 y0 = *(const ushort4*)(Y + (size_t)s0 * NCOL + q4);
            ushort4 y1 = *(const ushort4*)(Y + (size_t)s1 * NCOL + q4);
            ushort4 y2 = *(const ushort4*)(Y + (size_t)s2 * NCOL + q4);
            ushort4 y3 = *(const ushort4*)(Y + (size_t)s3 * NCOL + q4);
            a0.x += bf2f(y0.x); a0.y += bf2f(y0.y); a0.z += bf2f(y0.z); a0.w += bf2f(y0.w);
            a1.x += bf2f(y1.x); a1.y += bf2f(y1.y); a1.z += bf2f(y1.z); a1.w += bf2f(y1.w);
            a2.x += bf2f(y2.x); a2.y += bf2f(y2.y); a2.z += bf2f(y2.z); a2.w += bf2f(y2.w);
            a3.x += bf2f(y3.x); a3.y += bf2f(y3.y); a3.z += bf2f(y3.z); a3.w += bf2f(y3.w);
        }
        for (; e < e1; ++e) {
            ushort4 y = *(const ushort4*)(Y + (size_t)eidx[e] * NCOL + q4);
            a0.x += bf2f(y.x); a0.y += bf2f(y.y); a0.z += bf2f(y.z); a0.w += bf2f(y.w);
        }
        float invd = 1.0f / fmaxf((float)(e1 - e0), 1.0f);
        ushort4 r;
        r.x = f2bf(fmaxf((a0.x + a1.x + a2.x + a3.x) * invd + bf2f(sv.x) + b.x, 0.f));
        r.y = f2bf(fmaxf((a0.y + a1.y + a2.y + a3.y) * invd + bf2f(sv.y) + b.y, 0.f));
        r.z = f2bf(fmaxf((a0.z + a1.z + a2.z + a3.z) * invd + bf2f(sv.z) + b.z, 0.f));
        r.w = f2bf(fmaxf((a0.w + a1.w + a2.w + a3.w) * invd + bf2f(sv.w) + b.w, 0.f));
        *(ushort4*)(h + (size_t)v * HID + q4) = r;
    }
}

__global__ __launch_bounds__(256) void gather_kernel(const ushort* __restrict__ Y,
                                                     const int* __restrict__ off,
                                                     const int* __restrict__ eidx,
                                                     const float* __restrict__ bias,
                                                     ushort* __restrict__ h, int n_nodes) {
    int w = threadIdx.x >> 6;
    gather_body(Y, off, eidx, bias, h, n_nodes, blockIdx.x * 4 + w, gridDim.x * 4);
}

// ================= K2: gather2 + pool + head (cooperative) =====================
__global__ __launch_bounds__(256) void tail_kernel(
        const ushort* __restrict__ Y, const int* __restrict__ off,
        const int* __restrict__ eidx, const float* __restrict__ bias,
        ushort* __restrict__ h, const int* __restrict__ batch,
        float* __restrict__ pooled, float* __restrict__ cnt,
        const float* __restrict__ fc1w, const float* __restrict__ fc1b,
        const float* __restrict__ fc2w, const float* __restrict__ fc2b,
        float* __restrict__ out, int n_nodes) {
    cg::grid_group grid = cg::this_grid();
    int t = threadIdx.x, bid = blockIdx.x;
    int w = t >> 6;

    // ---- phase A: gather layer 2
    gather_body(Y, off, eidx, bias, h, n_nodes, bid * 4 + w, gridDim.x * 4);
    grid.sync();

    // ---- phase B: segmented mean-pool (batch sorted), 64-node chunks
    int npool = (n_nodes + 63) / 64;
    for (int c = bid; c < npool; c += gridDim.x) {
        int f = t;
        int v0 = c * 64;
        int vend = min(v0 + 64, n_nodes);
        int curg = batch[v0];
        float acc = 0.f, ac = 0.f;
        for (int v = v0; v < vend; ++v) {
            int g = batch[v];
            if (g != curg) {
                atomicAdd(&pooled[curg * HID + f], acc);
                if (f == 0) atomicAdd(&cnt[curg], ac);
                acc = 0.f; ac = 0.f; curg = g;
            }
            acc += bf2f(h[(size_t)v * HID + f]);
            ac += 1.0f;
        }
        atomicAdd(&pooled[curg * HID + f], acc);
        if (f == 0) atomicAdd(&cnt[curg], ac);
    }
    grid.sync();

    // ---- phase C: MLP head (16 graphs on blocks 0..15)
    __shared__ float p[256];
    __shared__ float hidv[128];
    if (bid < 16) {
        int g = bid;
        float inv = 1.0f / fmaxf(cnt[g], 1.0f);
        p[t] = pooled[g * HID + t] * inv;
        __syncthreads();
        if (t < 128) {
            float a = fc1b[t];
            for (int f = 0; f < 256; ++f) a += p[f] * fc1w[f * 128 + t];
            hidv[t] = fmaxf(a, 0.f);
        }
        __syncthreads();
        if (t < 2) {
            float o = fc2b[t];
            for (int k = 0; k < 128; ++k) o += hidv[k] * fc2w[k * 2 + t];
            out[g * 2 + t] = o;
        }
    }
}

extern "C" void kernel_launch(void* const* d_in, const int* in_sizes, int n_in,
                              void* d_out, int out_size, void* d_ws, size_t ws_size,
                              hipStream_t stream) {
    const float* x    = (const float*)d_in[0];
    const int*   ei   = (const int*)d_in[1];
    const int*   batch= (const int*)d_in[2];
    const float* W1n  = (const float*)d_in[3];
    const float* W1s  = (const float*)d_in[4];
    const float* b1   = (const float*)d_in[5];
    const float* W2n  = (const float*)d_in[6];
    const float* W2s  = (const float*)d_in[7];
    const float* b2   = (const float*)d_in[8];
    const float* fc1w = (const float*)d_in[9];
    const float* fc1b = (const float*)d_in[10];
    const float* fc2w = (const float*)d_in[11];
    const float* fc2b = (const float*)d_in[12];
    float* out = (float*)d_out;

    const int n_nodes = in_sizes[2];
    const int n_edges = in_sizes[1] / 2;
    const int in_dim  = in_sizes[0] / n_nodes;   // 512
    const int Mpad    = (n_nodes + 63) & ~63;    // 20032
    const int nb      = (n_nodes + 255) / 256;   // scan chunks
    const int* srcp = ei;
    const int* dstp = ei + n_edges;

    // workspace layout, 256B-aligned slices
    char* wsb = (char*)d_ws;
    size_t cur = 0;
    auto alloc = [&](size_t nbytes) { size_t o = cur; cur = (cur + nbytes + 255) & ~(size_t)255; return o; };
    size_t o_degi = alloc((size_t)n_nodes * 4);
    size_t o_off  = alloc((size_t)(n_nodes + 1) * 4);
    size_t o_cur  = alloc((size_t)n_nodes * 4);
    size_t o_part = alloc((size_t)nb * 4);
    size_t o_eidx = alloc((size_t)n_edges * 4);
    size_t o_w1   = alloc((size_t)NCOL * in_dim * 2);
    size_t o_w2   = alloc((size_t)NCOL * HID * 2);
    size_t o_xb   = alloc((size_t)Mpad * in_dim * 2);
    size_t o_hb   = alloc((size_t)Mpad * HID * 2);
    size_t o_y    = alloc((size_t)Mpad * NCOL * 2);
    size_t o_pool = alloc((size_t)16 * HID * 4 + 16 * 4);
    (void)ws_size;

    int*    degi    = (int*)(wsb + o_degi);
    int*    off     = (int*)(wsb + o_off);
    int*    cursor  = (int*)(wsb + o_cur);
    int*    partials= (int*)(wsb + o_part);
    int*    eidx    = (int*)(wsb + o_eidx);
    ushort* w1t     = (ushort*)(wsb + o_w1);
    ushort* w2t     = (ushort*)(wsb + o_w2);
    ushort* xb      = (ushort*)(wsb + o_xb);
    ushort* hb      = (ushort*)(wsb + o_hb);
    ushort* Y       = (ushort*)(wsb + o_y);
    float*  pooled  = (float*)(wsb + o_pool);
    float*  cnt     = pooled + 16 * HID;

    // ---- K1: prep + CSR (cooperative, 1024 blocks)
    int n4 = n_nodes * in_dim / 4;
    int n_zero_pool = 16 * HID + 16;
    int K1 = in_dim, K2 = HID;
    {
        void* args[] = {
            (void*)&x, (void*)&xb, (void*)&n4,
            (void*)&W1n, (void*)&W1s, (void*)&w1t, (void*)&K1,
            (void*)&W2n, (void*)&W2s, (void*)&w2t, (void*)&K2,
            (void*)&srcp, (void*)&dstp,
            (void*)&degi, (void*)&partials, (void*)&off, (void*)&cursor, (void*)&eidx,
            (void*)&pooled, (void*)&n_zero_pool,
            (void*)&n_nodes, (void*)&n_edges, (void*)&nb
        };
        hipLaunchCooperativeKernel((void*)prep_csr_kernel, dim3(1024), dim3(256),
                                   args, 0, stream);
    }

    dim3 gemm_grid(NCOL / 128, Mpad / 64);
    int gather_blocks = (n_nodes + 3) / 4;

    // ---- layer 1
    gemm_mfma<<<gemm_grid, 256, 0, stream>>>(xb, w1t, Y, in_dim);
    gather_kernel<<<gather_blocks, 256, 0, stream>>>(Y, off, eidx, b1, hb, n_nodes);

    // ---- layer 2 GEMM
    gemm_mfma<<<gemm_grid, 256, 0, stream>>>(hb, w2t, Y, HID);

    // ---- K2: gather2 + pool + head (cooperative, 1024 blocks)
    {
        void* args[] = {
            (void*)&Y, (void*)&off, (void*)&eidx, (void*)&b2,
            (void*)&hb, (void*)&batch, (void*)&pooled, (void*)&cnt,
            (void*)&fc1w, (void*)&fc1b, (void*)&fc2w, (void*)&fc2b,
            (void*)&out, (void*)&n_nodes
        };
        hipLaunchCooperativeKernel((void*)tail_kernel, dim3(1024), dim3(256),
                                   args, 0, stream);
    }
}

// Round 8
// 530.341 us; speedup vs baseline: 1.8556x; 1.8556x over previous
//
#include <hip/hip_runtime.h>
#include <hip/hip_bf16.h>

// GraphSAGE forward. R7: revert R6's cooperative kernels (grid.sync ~100us on
// gfx950 — 30x worse than a graph-node gap). R6 structure + XCD-aware GEMM
// swizzle (A-stripe sharers on one XCD) + pool fused into gather2 (no h2 write).

#define HID 256
#define NCOL 512

typedef __bf16 bf16x8 __attribute__((ext_vector_type(8)));
typedef float floatx4 __attribute__((ext_vector_type(4)));
typedef unsigned int u32;
typedef const u32 __attribute__((address_space(1)))* gp_t;
typedef u32 __attribute__((address_space(3)))* lp_t;

__device__ __forceinline__ ushort f2bf(float f) {   // round-to-nearest-even
    unsigned u = __float_as_uint(f);
    u += 0x7fffu + ((u >> 16) & 1u);
    return (ushort)(u >> 16);
}
__device__ __forceinline__ float bf2f(ushort b) {
    return __uint_as_float(((unsigned)b) << 16);
}

// ---------------- fused prep: [cvt x->bf16 | packT W1 | packT W2 | degree histogram]
__device__ __forceinline__ void packT_work(const float* __restrict__ Wn,
                                           const float* __restrict__ Ws,
                                           ushort* __restrict__ WT, int K, int gid) {
    if (gid >= NCOL * K) return;
    int n = gid / K, k = gid - n * K;
    float v = (n < HID) ? Wn[k * HID + n] : Ws[k * HID + (n - HID)];
    WT[gid] = f2bf(v);
}

__global__ void prep_kernel(const float* __restrict__ x, ushort* __restrict__ xb, int n4,
                            const float* __restrict__ W1n, const float* __restrict__ W1s,
                            ushort* __restrict__ w1t, int K1,
                            const float* __restrict__ W2n, const float* __restrict__ W2s,
                            ushort* __restrict__ w2t, int K2,
                            const int* __restrict__ dst, int* __restrict__ degi, int n_edges,
                            int nb_cvt, int nb_w1, int nb_w2) {
    int bx = blockIdx.x, t = threadIdx.x;
    if (bx < nb_cvt) {
        int i = bx * 256 + t;
        if (i < n4) {
            float4 v = ((const float4*)x)[i];
            ushort4 o;
            o.x = f2bf(v.x); o.y = f2bf(v.y); o.z = f2bf(v.z); o.w = f2bf(v.w);
            ((ushort4*)xb)[i] = o;
        }
    } else if (bx < nb_cvt + nb_w1) {
        packT_work(W1n, W1s, w1t, K1, (bx - nb_cvt) * 256 + t);
    } else if (bx < nb_cvt + nb_w1 + nb_w2) {
        packT_work(W2n, W2s, w2t, K2, (bx - nb_cvt - nb_w1) * 256 + t);
    } else {
        int e = (bx - nb_cvt - nb_w1 - nb_w2) * 256 + t;
        if (e < n_edges) atomicAdd(&degi[dst[e]], 1);
    }
}

// ---------------- scan phase 1: per-256-chunk sums
__global__ __launch_bounds__(256) void psum_kernel(const int* __restrict__ degi,
                                                   int* __restrict__ partials, int n) {
    int t = threadIdx.x;
    int i = blockIdx.x * 256 + t;
    int v = (i < n) ? degi[i] : 0;
#pragma unroll
    for (int d = 1; d < 64; d <<= 1) v += __shfl_xor(v, d, 64);
    __shared__ int wsum[4];
    if ((t & 63) == 0) wsum[t >> 6] = v;
    __syncthreads();
    if (t == 0) partials[blockIdx.x] = wsum[0] + wsum[1] + wsum[2] + wsum[3];
}

// ---------------- scan phase 2: 1-wave exclusive scan of partials (in place)
__global__ __launch_bounds__(64) void pscan_kernel(int* __restrict__ partials,
                                                   int* __restrict__ off, int nb, int n) {
    int lane = threadIdx.x;
    int carry = 0;
    for (int base = 0; base < nb; base += 256) {
        int i0 = base + lane * 4;
        int v0 = (i0 + 0 < nb) ? partials[i0 + 0] : 0;
        int v1 = (i0 + 1 < nb) ? partials[i0 + 1] : 0;
        int v2 = (i0 + 2 < nb) ? partials[i0 + 2] : 0;
        int v3 = (i0 + 3 < nb) ? partials[i0 + 3] : 0;
        int local = v0 + v1 + v2 + v3;
        int s = local;
#pragma unroll
        for (int d = 1; d < 64; d <<= 1) {
            int t = __shfl_up(s, d, 64);
            if (lane >= d) s += t;
        }
        int excl = carry + s - local;
        if (i0 + 0 < nb) partials[i0 + 0] = excl;
        excl += v0;
        if (i0 + 1 < nb) partials[i0 + 1] = excl;
        excl += v1;
        if (i0 + 2 < nb) partials[i0 + 2] = excl;
        excl += v2;
        if (i0 + 3 < nb) partials[i0 + 3] = excl;
        carry += __shfl(s, 63, 64);
    }
    if (lane == 0) off[n] = carry;
}

// ---------------- scan phase 3: per-chunk rescan + chunk offset -> off, cursor
__global__ __launch_bounds__(256) void scan2_kernel(const int* __restrict__ degi,
                                                    const int* __restrict__ partials,
                                                    int* __restrict__ off,
                                                    int* __restrict__ cursor, int n) {
    int t = threadIdx.x, lane = t & 63, w = t >> 6;
    int i = blockIdx.x * 256 + t;
    int v = (i < n) ? degi[i] : 0;
    int s = v;
#pragma unroll
    for (int d = 1; d < 64; d <<= 1) {
        int u = __shfl_up(s, d, 64);
        if (lane >= d) s += u;
    }
    __shared__ int wsum[4];
    if (lane == 63) wsum[w] = s;
    __syncthreads();
    int woff = 0;
    for (int k = 0; k < w; ++k) woff += wsum[k];
    int excl = partials[blockIdx.x] + woff + s - v;
    if (i < n) { off[i] = excl; cursor[i] = excl; }
}

// ---------------- CSR fill: eidx[pos] = src[e], pos = cursor[dst[e]]++
__global__ void fill_kernel(const int* __restrict__ src, const int* __restrict__ dst,
                            int* __restrict__ cursor, int* __restrict__ eidx, int n_edges) {
    int e = blockIdx.x * 256 + threadIdx.x;
    if (e < n_edges) {
        int p = atomicAdd(&cursor[dst[e]], 1);
        eidx[p] = src[e];
    }
}

// ---------------- bf16 MFMA GEMM: Y[Mpad,512] = A[Mpad,K] @ BT[512,K]^T (bf16 out)
// 64x128 tile, 4 waves (2x2 of 32x64), BK=64, dbuf global_load_lds, XOR swizzle.
// 1D grid, XCD-aware: the 4 N-tiles sharing an A-stripe get the same b%8 (same XCD)
// so A is HBM-fetched once per stripe, L2-hit for the other 3.
__global__ __launch_bounds__(256) void gemm_mfma(const ushort* __restrict__ A,
                                                 const ushort* __restrict__ BT,
                                                 ushort* __restrict__ Y, int K, int nG) {
    int b = blockIdx.x;
    int xcd = b & 7, rest = b >> 3;
    int m = rest & 3, Ggrp = rest >> 2;
    int G = xcd + 8 * Ggrp;                    // A-stripe id
    if (G >= nG) return;
    int m0 = G * 64, n0 = m * 128;

    __shared__ ushort As[2][64 * 64];
    __shared__ ushort Bs[2][128 * 64];
    int tid = threadIdx.x;
    int w = tid >> 6, lane = tid & 63;
    int quad = lane >> 4, r16 = lane & 15;
    int wm = (w >> 1) * 32, wn = (w & 1) * 64;

    int arow[2], agu[2], brow[4], bgu[4];
#pragma unroll
    for (int rr = 0; rr < 2; ++rr) {
        int idx = rr * 256 + tid;
        arow[rr] = idx >> 3;
        agu[rr] = (idx & 7) ^ (arow[rr] & 7);
    }
#pragma unroll
    for (int rr = 0; rr < 4; ++rr) {
        int idx = rr * 256 + tid;
        brow[rr] = idx >> 3;
        bgu[rr] = (idx & 7) ^ (brow[rr] & 7);
    }

    auto stage = [&](int buf, int k0) {
#pragma unroll
        for (int rr = 0; rr < 2; ++rr) {
            const ushort* ga = A + (size_t)(m0 + arow[rr]) * K + k0 + agu[rr] * 8;
            ushort* la = As[buf] + (size_t)(rr * 256 + w * 64) * 8;
            __builtin_amdgcn_global_load_lds((gp_t)(const void*)ga, (lp_t)(void*)la, 16, 0, 0);
        }
#pragma unroll
        for (int rr = 0; rr < 4; ++rr) {
            const ushort* gb = BT + (size_t)(n0 + brow[rr]) * K + k0 + bgu[rr] * 8;
            ushort* lb = Bs[buf] + (size_t)(rr * 256 + w * 64) * 8;
            __builtin_amdgcn_global_load_lds((gp_t)(const void*)gb, (lp_t)(void*)lb, 16, 0, 0);
        }
    };

    floatx4 acc[2][4];
#pragma unroll
    for (int i = 0; i < 2; ++i)
#pragma unroll
        for (int j = 0; j < 4; ++j) acc[i][j] = (floatx4){0.f, 0.f, 0.f, 0.f};

    const int nk = K >> 6;
    stage(0, 0);
    for (int t = 0; t < nk; ++t) {
        int cb = t & 1;
        __syncthreads();
        if (t + 1 < nk) stage(cb ^ 1, (t + 1) << 6);
        const ushort* Ab = As[cb];
        const ushort* Bb = Bs[cb];
#pragma unroll
        for (int s = 0; s < 2; ++s) {
            bf16x8 a[2], b2[4];
#pragma unroll
            for (int i = 0; i < 2; ++i) {
                int row = wm + i * 16 + r16;
                int au = (s * 4 + quad) ^ (row & 7);
                a[i] = *(const bf16x8*)(Ab + row * 64 + au * 8);
            }
#pragma unroll
            for (int j = 0; j < 4; ++j) {
                int row = wn + j * 16 + r16;
                int bu = (s * 4 + quad) ^ (row & 7);
                b2[j] = *(const bf16x8*)(Bb + row * 64 + bu * 8);
            }
#pragma unroll
            for (int i = 0; i < 2; ++i)
#pragma unroll
                for (int j = 0; j < 4; ++j)
                    acc[i][j] = __builtin_amdgcn_mfma_f32_16x16x32_bf16(a[i], b2[j], acc[i][j], 0, 0, 0);
        }
    }
#pragma unroll
    for (int i = 0; i < 2; ++i)
#pragma unroll
        for (int j = 0; j < 4; ++j) {
            int col = n0 + wn + j * 16 + r16;
#pragma unroll
            for (int rg = 0; rg < 4; ++rg) {
                int row = m0 + wm + i * 16 + quad * 4 + rg;
                Y[(size_t)row * NCOL + col] = f2bf(acc[i][j][rg]);
            }
        }
}

// ---------------- gather core: returns fp32 combined row chunk for node v
__device__ __forceinline__ float4 gather_row(const ushort* __restrict__ Y,
                                             const int* __restrict__ off,
                                             const int* __restrict__ eidx,
                                             const float* __restrict__ bias,
                                             int v, int q4) {
    int e0 = off[v], e1 = off[v + 1];
    ushort4 sv = *(const ushort4*)(Y + (size_t)v * NCOL + HID + q4);
    float4 b = *(const float4*)(bias + q4);
    float4 a0 = make_float4(0.f, 0.f, 0.f, 0.f), a1 = a0, a2 = a0, a3 = a0;
    int e = e0;
    for (; e + 3 < e1; e += 4) {
        int s0 = eidx[e], s1 = eidx[e + 1], s2 = eidx[e + 2], s3 = eidx[e + 3];
        ushort4 y0 = *(const ushort4*)(Y + (size_t)s0 * NCOL + q4);
        ushort4 y1 = *(const ushort4*)(Y + (size_t)s1 * NCOL + q4);
        ushort4 y2 = *(const ushort4*)(Y + (size_t)s2 * NCOL + q4);
        ushort4 y3 = *(const ushort4*)(Y + (size_t)s3 * NCOL + q4);
        a0.x += bf2f(y0.x); a0.y += bf2f(y0.y); a0.z += bf2f(y0.z); a0.w += bf2f(y0.w);
        a1.x += bf2f(y1.x); a1.y += bf2f(y1.y); a1.z += bf2f(y1.z); a1.w += bf2f(y1.w);
        a2.x += bf2f(y2.x); a2.y += bf2f(y2.y); a2.z += bf2f(y2.z); a2.w += bf2f(y2.w);
        a3.x += bf2f(y3.x); a3.y += bf2f(y3.y); a3.z += bf2f(y3.z); a3.w += bf2f(y3.w);
    }
    for (; e < e1; ++e) {
        ushort4 y = *(const ushort4*)(Y + (size_t)eidx[e] * NCOL + q4);
        a0.x += bf2f(y.x); a0.y += bf2f(y.y); a0.z += bf2f(y.z); a0.w += bf2f(y.w);
    }
    float invd = 1.0f / fmaxf((float)(e1 - e0), 1.0f);
    float4 r;
    r.x = fmaxf((a0.x + a1.x + a2.x + a3.x) * invd + bf2f(sv.x) + b.x, 0.f);
    r.y = fmaxf((a0.y + a1.y + a2.y + a3.y) * invd + bf2f(sv.y) + b.y, 0.f);
    r.z = fmaxf((a0.z + a1.z + a2.z + a3.z) * invd + bf2f(sv.z) + b.z, 0.f);
    r.w = fmaxf((a0.w + a1.w + a2.w + a3.w) * invd + bf2f(sv.w) + b.w, 0.f);
    return r;
}

// ---------------- layer-1 gather: writes bf16 h
__global__ __launch_bounds__(256) void gather_kernel(const ushort* __restrict__ Y,
                                                     const int* __restrict__ off,
                                                     const int* __restrict__ eidx,
                                                     const float* __restrict__ bias,
                                                     ushort* __restrict__ h, int n_nodes) {
    int tid = threadIdx.x;
    int v = blockIdx.x * 4 + (tid >> 6);
    if (v >= n_nodes) return;
    int q4 = (tid & 63) << 2;
    float4 r = gather_row(Y, off, eidx, bias, v, q4);
    ushort4 o;
    o.x = f2bf(r.x); o.y = f2bf(r.y); o.z = f2bf(r.z); o.w = f2bf(r.w);
    *(ushort4*)(h + (size_t)v * HID + q4) = o;
}

// ---------------- layer-2 gather fused with mean-pool: atomicAdd fp32 row to pooled
__global__ __launch_bounds__(256) void gather_pool_kernel(const ushort* __restrict__ Y,
                                                          const int* __restrict__ off,
                                                          const int* __restrict__ eidx,
                                                          const float* __restrict__ bias,
                                                          const int* __restrict__ batch,
                                                          float* __restrict__ pooled,
                                                          float* __restrict__ cnt, int n_nodes) {
    int tid = threadIdx.x;
    int v = blockIdx.x * 4 + (tid >> 6);
    if (v >= n_nodes) return;
    int q4 = (tid & 63) << 2;
    float4 r = gather_row(Y, off, eidx, bias, v, q4);
    int g = batch[v];
    float* p = pooled + g * HID + q4;
    atomicAdd(p + 0, r.x); atomicAdd(p + 1, r.y);
    atomicAdd(p + 2, r.z); atomicAdd(p + 3, r.w);
    if ((tid & 63) == 0) atomicAdd(&cnt[g], 1.0f);
}

// ---------------- MLP head: out[g] = relu(pooled_mean @ fc1w + fc1b) @ fc2w + fc2b
__global__ void head_kernel(const float* __restrict__ pooled, const float* __restrict__ cnt,
                            const float* __restrict__ fc1w, const float* __restrict__ fc1b,
                            const float* __restrict__ fc2w, const float* __restrict__ fc2b,
                            float* __restrict__ out) {
    int g = blockIdx.x, j = threadIdx.x;     // 128 threads
    __shared__ float p[256];
    __shared__ float hid[128];
    float inv = 1.0f / fmaxf(cnt[g], 1.0f);
    p[j] = pooled[g * HID + j] * inv;
    p[j + 128] = pooled[g * HID + 128 + j] * inv;
    __syncthreads();
    float a = fc1b[j];
    for (int f = 0; f < 256; ++f) a += p[f] * fc1w[f * 128 + j];
    hid[j] = fmaxf(a, 0.f);
    __syncthreads();
    if (j < 2) {
        float o = fc2b[j];
        for (int t = 0; t < 128; ++t) o += hid[t] * fc2w[t * 2 + j];
        out[g * 2 + j] = o;
    }
}

extern "C" void kernel_launch(void* const* d_in, const int* in_sizes, int n_in,
                              void* d_out, int out_size, void* d_ws, size_t ws_size,
                              hipStream_t stream) {
    const float* x    = (const float*)d_in[0];
    const int*   ei   = (const int*)d_in[1];
    const int*   batch= (const int*)d_in[2];
    const float* W1n  = (const float*)d_in[3];
    const float* W1s  = (const float*)d_in[4];
    const float* b1   = (const float*)d_in[5];
    const float* W2n  = (const float*)d_in[6];
    const float* W2s  = (const float*)d_in[7];
    const float* b2   = (const float*)d_in[8];
    const float* fc1w = (const float*)d_in[9];
    const float* fc1b = (const float*)d_in[10];
    const float* fc2w = (const float*)d_in[11];
    const float* fc2b = (const float*)d_in[12];
    float* out = (float*)d_out;

    const int n_nodes = in_sizes[2];
    const int n_edges = in_sizes[1] / 2;
    const int in_dim  = in_sizes[0] / n_nodes;   // 512
    const int Mpad    = (n_nodes + 63) & ~63;    // 20032
    const int nb      = (n_nodes + 255) / 256;   // scan chunks
    const int nG      = Mpad / 64;               // A-stripes (313)
    const int* src = ei;
    const int* dst = ei + n_edges;

    // workspace layout, 256B-aligned slices
    char* wsb = (char*)d_ws;
    size_t cur = 0;
    auto alloc = [&](size_t nbytes) { size_t o = cur; cur = (cur + nbytes + 255) & ~(size_t)255; return o; };
    size_t o_degi = alloc((size_t)n_nodes * 4);
    size_t o_off  = alloc((size_t)(n_nodes + 1) * 4);
    size_t o_cur  = alloc((size_t)n_nodes * 4);
    size_t o_part = alloc((size_t)nb * 4);
    size_t o_eidx = alloc((size_t)n_edges * 4);
    size_t o_w1   = alloc((size_t)NCOL * in_dim * 2);
    size_t o_w2   = alloc((size_t)NCOL * HID * 2);
    size_t o_xb   = alloc((size_t)Mpad * in_dim * 2);
    size_t o_hb   = alloc((size_t)Mpad * HID * 2);
    size_t o_y    = alloc((size_t)Mpad * NCOL * 2);
    size_t o_pool = alloc((size_t)16 * HID * 4 + 16 * 4);
    (void)ws_size;

    int*    degi    = (int*)(wsb + o_degi);
    int*    off     = (int*)(wsb + o_off);
    int*    cursor  = (int*)(wsb + o_cur);
    int*    partials= (int*)(wsb + o_part);
    int*    eidx    = (int*)(wsb + o_eidx);
    ushort* w1t     = (ushort*)(wsb + o_w1);
    ushort* w2t     = (ushort*)(wsb + o_w2);
    ushort* xb      = (ushort*)(wsb + o_xb);
    ushort* hb      = (ushort*)(wsb + o_hb);
    ushort* Y       = (ushort*)(wsb + o_y);
    float*  pooled  = (float*)(wsb + o_pool);
    float*  cnt     = pooled + 16 * HID;

    hipMemsetAsync(degi, 0, (size_t)n_nodes * 4, stream);
    hipMemsetAsync(pooled, 0, (size_t)(16 * HID + 16) * 4, stream);

    // ---- fused prep: cvt | packT W1 | packT W2 | degree histogram
    int n4 = n_nodes * in_dim / 4;
    int nb_cvt = (n4 + 255) / 256;
    int nb_w1  = (NCOL * in_dim + 255) / 256;
    int nb_w2  = (NCOL * HID + 255) / 256;
    int nb_deg = (n_edges + 255) / 256;
    prep_kernel<<<nb_cvt + nb_w1 + nb_w2 + nb_deg, 256, 0, stream>>>(
        x, xb, n4, W1n, W1s, w1t, in_dim, W2n, W2s, w2t, HID,
        dst, degi, n_edges, nb_cvt, nb_w1, nb_w2);

    // ---- CSR build: hierarchical scan -> fill
    psum_kernel<<<nb, 256, 0, stream>>>(degi, partials, n_nodes);
    pscan_kernel<<<1, 64, 0, stream>>>(partials, off, nb, n_nodes);
    scan2_kernel<<<nb, 256, 0, stream>>>(degi, partials, off, cursor, n_nodes);
    fill_kernel<<<(n_edges + 255) / 256, 256, 0, stream>>>(src, dst, cursor, eidx, n_edges);

    // XCD-grouped 1D gemm grid: 8 * 4 * ceil(nG/8) blocks
    int gemm_blocks = 8 * 4 * ((nG + 7) / 8);
    int gather_blocks = (n_nodes + 3) / 4;

    // ---- layer 1
    gemm_mfma<<<gemm_blocks, 256, 0, stream>>>(xb, w1t, Y, in_dim, nG);
    gather_kernel<<<gather_blocks, 256, 0, stream>>>(Y, off, eidx, b1, hb, n_nodes);

    // ---- layer 2 + fused pool
    gemm_mfma<<<gemm_blocks, 256, 0, stream>>>(hb, w2t, Y, HID, nG);
    gather_pool_kernel<<<gather_blocks, 256, 0, stream>>>(Y, off, eidx, b2, batch,
                                                          pooled, cnt, n_nodes);

    // ---- head
    head_kernel<<<16, 128, 0, stream>>>(pooled, cnt, fc1w, fc1b, fc2w, fc2b, out);
}

// Round 9
// 229.677 us; speedup vs baseline: 4.2846x; 2.3091x over previous
//
#include <hip/hip_runtime.h>
#include <hip/hip_bf16.h>

// GraphSAGE forward. R8: revert R7's gather+pool fusion (5.1M atomics onto 4K
// addresses = 340us serialization). R6 dataflow (separate gather2/pool/head),
// keep R7's XCD-grouped GEMM grid (A-stripe sharers on one XCD).

#define HID 256
#define NCOL 512

typedef __bf16 bf16x8 __attribute__((ext_vector_type(8)));
typedef float floatx4 __attribute__((ext_vector_type(4)));
typedef unsigned int u32;
typedef const u32 __attribute__((address_space(1)))* gp_t;
typedef u32 __attribute__((address_space(3)))* lp_t;

__device__ __forceinline__ ushort f2bf(float f) {   // round-to-nearest-even
    unsigned u = __float_as_uint(f);
    u += 0x7fffu + ((u >> 16) & 1u);
    return (ushort)(u >> 16);
}
__device__ __forceinline__ float bf2f(ushort b) {
    return __uint_as_float(((unsigned)b) << 16);
}

// ---------------- fused prep: [cvt x->bf16 | packT W1 | packT W2 | degree histogram]
__device__ __forceinline__ void packT_work(const float* __restrict__ Wn,
                                           const float* __restrict__ Ws,
                                           ushort* __restrict__ WT, int K, int gid) {
    if (gid >= NCOL * K) return;
    int n = gid / K, k = gid - n * K;
    float v = (n < HID) ? Wn[k * HID + n] : Ws[k * HID + (n - HID)];
    WT[gid] = f2bf(v);
}

__global__ void prep_kernel(const float* __restrict__ x, ushort* __restrict__ xb, int n4,
                            const float* __restrict__ W1n, const float* __restrict__ W1s,
                            ushort* __restrict__ w1t, int K1,
                            const float* __restrict__ W2n, const float* __restrict__ W2s,
                            ushort* __restrict__ w2t, int K2,
                            const int* __restrict__ dst, int* __restrict__ degi, int n_edges,
                            int nb_cvt, int nb_w1, int nb_w2) {
    int bx = blockIdx.x, t = threadIdx.x;
    if (bx < nb_cvt) {
        int i = bx * 256 + t;
        if (i < n4) {
            float4 v = ((const float4*)x)[i];
            ushort4 o;
            o.x = f2bf(v.x); o.y = f2bf(v.y); o.z = f2bf(v.z); o.w = f2bf(v.w);
            ((ushort4*)xb)[i] = o;
        }
    } else if (bx < nb_cvt + nb_w1) {
        packT_work(W1n, W1s, w1t, K1, (bx - nb_cvt) * 256 + t);
    } else if (bx < nb_cvt + nb_w1 + nb_w2) {
        packT_work(W2n, W2s, w2t, K2, (bx - nb_cvt - nb_w1) * 256 + t);
    } else {
        int e = (bx - nb_cvt - nb_w1 - nb_w2) * 256 + t;
        if (e < n_edges) atomicAdd(&degi[dst[e]], 1);
    }
}

// ---------------- scan phase 1: per-256-chunk sums
__global__ __launch_bounds__(256) void psum_kernel(const int* __restrict__ degi,
                                                   int* __restrict__ partials, int n) {
    int t = threadIdx.x;
    int i = blockIdx.x * 256 + t;
    int v = (i < n) ? degi[i] : 0;
#pragma unroll
    for (int d = 1; d < 64; d <<= 1) v += __shfl_xor(v, d, 64);
    __shared__ int wsum[4];
    if ((t & 63) == 0) wsum[t >> 6] = v;
    __syncthreads();
    if (t == 0) partials[blockIdx.x] = wsum[0] + wsum[1] + wsum[2] + wsum[3];
}

// ---------------- scan phase 2: 1-wave exclusive scan of partials (in place)
__global__ __launch_bounds__(64) void pscan_kernel(int* __restrict__ partials,
                                                   int* __restrict__ off, int nb, int n) {
    int lane = threadIdx.x;
    int carry = 0;
    for (int base = 0; base < nb; base += 256) {
        int i0 = base + lane * 4;
        int v0 = (i0 + 0 < nb) ? partials[i0 + 0] : 0;
        int v1 = (i0 + 1 < nb) ? partials[i0 + 1] : 0;
        int v2 = (i0 + 2 < nb) ? partials[i0 + 2] : 0;
        int v3 = (i0 + 3 < nb) ? partials[i0 + 3] : 0;
        int local = v0 + v1 + v2 + v3;
        int s = local;
#pragma unroll
        for (int d = 1; d < 64; d <<= 1) {
            int t = __shfl_up(s, d, 64);
            if (lane >= d) s += t;
        }
        int excl = carry + s - local;
        if (i0 + 0 < nb) partials[i0 + 0] = excl;
        excl += v0;
        if (i0 + 1 < nb) partials[i0 + 1] = excl;
        excl += v1;
        if (i0 + 2 < nb) partials[i0 + 2] = excl;
        excl += v2;
        if (i0 + 3 < nb) partials[i0 + 3] = excl;
        carry += __shfl(s, 63, 64);
    }
    if (lane == 0) off[n] = carry;
}

// ---------------- scan phase 3: per-chunk rescan + chunk offset -> off, cursor
__global__ __launch_bounds__(256) void scan2_kernel(const int* __restrict__ degi,
                                                    const int* __restrict__ partials,
                                                    int* __restrict__ off,
                                                    int* __restrict__ cursor, int n) {
    int t = threadIdx.x, lane = t & 63, w = t >> 6;
    int i = blockIdx.x * 256 + t;
    int v = (i < n) ? degi[i] : 0;
    int s = v;
#pragma unroll
    for (int d = 1; d < 64; d <<= 1) {
        int u = __shfl_up(s, d, 64);
        if (lane >= d) s += u;
    }
    __shared__ int wsum[4];
    if (lane == 63) wsum[w] = s;
    __syncthreads();
    int woff = 0;
    for (int k = 0; k < w; ++k) woff += wsum[k];
    int excl = partials[blockIdx.x] + woff + s - v;
    if (i < n) { off[i] = excl; cursor[i] = excl; }
}

// ---------------- CSR fill: eidx[pos] = src[e], pos = cursor[dst[e]]++
__global__ void fill_kernel(const int* __restrict__ src, const int* __restrict__ dst,
                            int* __restrict__ cursor, int* __restrict__ eidx, int n_edges) {
    int e = blockIdx.x * 256 + threadIdx.x;
    if (e < n_edges) {
        int p = atomicAdd(&cursor[dst[e]], 1);
        eidx[p] = src[e];
    }
}

// ---------------- bf16 MFMA GEMM: Y[Mpad,512] = A[Mpad,K] @ BT[512,K]^T (bf16 out)
// 64x128 tile, 4 waves (2x2 of 32x64), BK=64, dbuf global_load_lds, XOR swizzle.
// 1D grid, XCD-aware: the 4 N-tiles sharing an A-stripe get the same b%8 (same XCD).
__global__ __launch_bounds__(256) void gemm_mfma(const ushort* __restrict__ A,
                                                 const ushort* __restrict__ BT,
                                                 ushort* __restrict__ Y, int K, int nG) {
    int b = blockIdx.x;
    int xcd = b & 7, rest = b >> 3;
    int m = rest & 3, Ggrp = rest >> 2;
    int G = xcd + 8 * Ggrp;                    // A-stripe id
    if (G >= nG) return;
    int m0 = G * 64, n0 = m * 128;

    __shared__ ushort As[2][64 * 64];
    __shared__ ushort Bs[2][128 * 64];
    int tid = threadIdx.x;
    int w = tid >> 6, lane = tid & 63;
    int quad = lane >> 4, r16 = lane & 15;
    int wm = (w >> 1) * 32, wn = (w & 1) * 64;

    int arow[2], agu[2], brow[4], bgu[4];
#pragma unroll
    for (int rr = 0; rr < 2; ++rr) {
        int idx = rr * 256 + tid;
        arow[rr] = idx >> 3;
        agu[rr] = (idx & 7) ^ (arow[rr] & 7);
    }
#pragma unroll
    for (int rr = 0; rr < 4; ++rr) {
        int idx = rr * 256 + tid;
        brow[rr] = idx >> 3;
        bgu[rr] = (idx & 7) ^ (brow[rr] & 7);
    }

    auto stage = [&](int buf, int k0) {
#pragma unroll
        for (int rr = 0; rr < 2; ++rr) {
            const ushort* ga = A + (size_t)(m0 + arow[rr]) * K + k0 + agu[rr] * 8;
            ushort* la = As[buf] + (size_t)(rr * 256 + w * 64) * 8;
            __builtin_amdgcn_global_load_lds((gp_t)(const void*)ga, (lp_t)(void*)la, 16, 0, 0);
        }
#pragma unroll
        for (int rr = 0; rr < 4; ++rr) {
            const ushort* gb = BT + (size_t)(n0 + brow[rr]) * K + k0 + bgu[rr] * 8;
            ushort* lb = Bs[buf] + (size_t)(rr * 256 + w * 64) * 8;
            __builtin_amdgcn_global_load_lds((gp_t)(const void*)gb, (lp_t)(void*)lb, 16, 0, 0);
        }
    };

    floatx4 acc[2][4];
#pragma unroll
    for (int i = 0; i < 2; ++i)
#pragma unroll
        for (int j = 0; j < 4; ++j) acc[i][j] = (floatx4){0.f, 0.f, 0.f, 0.f};

    const int nk = K >> 6;
    stage(0, 0);
    for (int t = 0; t < nk; ++t) {
        int cb = t & 1;
        __syncthreads();
        if (t + 1 < nk) stage(cb ^ 1, (t + 1) << 6);
        const ushort* Ab = As[cb];
        const ushort* Bb = Bs[cb];
#pragma unroll
        for (int s = 0; s < 2; ++s) {
            bf16x8 a[2], b2[4];
#pragma unroll
            for (int i = 0; i < 2; ++i) {
                int row = wm + i * 16 + r16;
                int au = (s * 4 + quad) ^ (row & 7);
                a[i] = *(const bf16x8*)(Ab + row * 64 + au * 8);
            }
#pragma unroll
            for (int j = 0; j < 4; ++j) {
                int row = wn + j * 16 + r16;
                int bu = (s * 4 + quad) ^ (row & 7);
                b2[j] = *(const bf16x8*)(Bb + row * 64 + bu * 8);
            }
#pragma unroll
            for (int i = 0; i < 2; ++i)
#pragma unroll
                for (int j = 0; j < 4; ++j)
                    acc[i][j] = __builtin_amdgcn_mfma_f32_16x16x32_bf16(a[i], b2[j], acc[i][j], 0, 0, 0);
        }
    }
#pragma unroll
    for (int i = 0; i < 2; ++i)
#pragma unroll
        for (int j = 0; j < 4; ++j) {
            int col = n0 + wn + j * 16 + r16;
#pragma unroll
            for (int rg = 0; rg < 4; ++rg) {
                int row = m0 + wm + i * 16 + quad * 4 + rg;
                Y[(size_t)row * NCOL + col] = f2bf(acc[i][j][rg]);
            }
        }
}

// ---------------- fused gather + combine: one 64-lane wave per node, unroll-4
__global__ __launch_bounds__(256) void gather_kernel(const ushort* __restrict__ Y,
                                                     const int* __restrict__ off,
                                                     const int* __restrict__ eidx,
                                                     const float* __restrict__ bias,
                                                     ushort* __restrict__ h, int n_nodes) {
    int tid = threadIdx.x;
    int v = blockIdx.x * 4 + (tid >> 6);
    if (v >= n_nodes) return;
    int q4 = (tid & 63) << 2;
    int e0 = off[v], e1 = off[v + 1];
    ushort4 sv = *(const ushort4*)(Y + (size_t)v * NCOL + HID + q4);   // self (bf16)
    float4 b = *(const float4*)(bias + q4);
    float4 a0 = make_float4(0.f, 0.f, 0.f, 0.f), a1 = a0, a2 = a0, a3 = a0;
    int e = e0;
    for (; e + 3 < e1; e += 4) {
        int s0 = eidx[e], s1 = eidx[e + 1], s2 = eidx[e + 2], s3 = eidx[e + 3];
        ushort4 y0 = *(const ushort4*)(Y + (size_t)s0 * NCOL + q4);
        ushort4 y1 = *(const ushort4*)(Y + (size_t)s1 * NCOL + q4);
        ushort4 y2 = *(const ushort4*)(Y + (size_t)s2 * NCOL + q4);
        ushort4 y3 = *(const ushort4*)(Y + (size_t)s3 * NCOL + q4);
        a0.x += bf2f(y0.x); a0.y += bf2f(y0.y); a0.z += bf2f(y0.z); a0.w += bf2f(y0.w);
        a1.x += bf2f(y1.x); a1.y += bf2f(y1.y); a1.z += bf2f(y1.z); a1.w += bf2f(y1.w);
        a2.x += bf2f(y2.x); a2.y += bf2f(y2.y); a2.z += bf2f(y2.z); a2.w += bf2f(y2.w);
        a3.x += bf2f(y3.x); a3.y += bf2f(y3.y); a3.z += bf2f(y3.z); a3.w += bf2f(y3.w);
    }
    for (; e < e1; ++e) {
        ushort4 y = *(const ushort4*)(Y + (size_t)eidx[e] * NCOL + q4);
        a0.x += bf2f(y.x); a0.y += bf2f(y.y); a0.z += bf2f(y.z); a0.w += bf2f(y.w);
    }
    float invd = 1.0f / fmaxf((float)(e1 - e0), 1.0f);
    ushort4 r;
    r.x = f2bf(fmaxf((a0.x + a1.x + a2.x + a3.x) * invd + bf2f(sv.x) + b.x, 0.f));
    r.y = f2bf(fmaxf((a0.y + a1.y + a2.y + a3.y) * invd + bf2f(sv.y) + b.y, 0.f));
    r.z = f2bf(fmaxf((a0.z + a1.z + a2.z + a3.z) * invd + bf2f(sv.z) + b.z, 0.f));
    r.w = f2bf(fmaxf((a0.w + a1.w + a2.w + a3.w) * invd + bf2f(sv.w) + b.w, 0.f));
    *(ushort4*)(h + (size_t)v * HID + q4) = r;
}

// ---------------- segmented mean-pool (batch sorted), bf16 in, fp32 accumulate
__global__ void pool_kernel(const ushort* __restrict__ h, const int* __restrict__ batch,
                            float* __restrict__ pooled, float* __restrict__ cnt, int n_nodes) {
    int f = threadIdx.x;                     // 256 features
    int v0 = blockIdx.x * 64;
    int vend = min(v0 + 64, n_nodes);
    if (v0 >= n_nodes) return;
    int cur = batch[v0];
    float acc = 0.f, ac = 0.f;
    for (int v = v0; v < vend; ++v) {
        int g = batch[v];
        if (g != cur) {
            atomicAdd(&pooled[cur * HID + f], acc);
            if (f == 0) atomicAdd(&cnt[cur], ac);
            acc = 0.f; ac = 0.f; cur = g;
        }
        acc += bf2f(h[(size_t)v * HID + f]);
        ac += 1.0f;
    }
    atomicAdd(&pooled[cur * HID + f], acc);
    if (f == 0) atomicAdd(&cnt[cur], ac);
}

// ---------------- MLP head: out[g] = relu(pooled_mean @ fc1w + fc1b) @ fc2w + fc2b
__global__ void head_kernel(const float* __restrict__ pooled, const float* __restrict__ cnt,
                            const float* __restrict__ fc1w, const float* __restrict__ fc1b,
                            const float* __restrict__ fc2w, const float* __restrict__ fc2b,
                            float* __restrict__ out) {
    int g = blockIdx.x, j = threadIdx.x;     // 128 threads
    __shared__ float p[256];
    __shared__ float hid[128];
    float inv = 1.0f / fmaxf(cnt[g], 1.0f);
    p[j] = pooled[g * HID + j] * inv;
    p[j + 128] = pooled[g * HID + 128 + j] * inv;
    __syncthreads();
    float a = fc1b[j];
    for (int f = 0; f < 256; ++f) a += p[f] * fc1w[f * 128 + j];
    hid[j] = fmaxf(a, 0.f);
    __syncthreads();
    if (j < 2) {
        float o = fc2b[j];
        for (int t = 0; t < 128; ++t) o += hid[t] * fc2w[t * 2 + j];
        out[g * 2 + j] = o;
    }
}

extern "C" void kernel_launch(void* const* d_in, const int* in_sizes, int n_in,
                              void* d_out, int out_size, void* d_ws, size_t ws_size,
                              hipStream_t stream) {
    const float* x    = (const float*)d_in[0];
    const int*   ei   = (const int*)d_in[1];
    const int*   batch= (const int*)d_in[2];
    const float* W1n  = (const float*)d_in[3];
    const float* W1s  = (const float*)d_in[4];
    const float* b1   = (const float*)d_in[5];
    const float* W2n  = (const float*)d_in[6];
    const float* W2s  = (const float*)d_in[7];
    const float* b2   = (const float*)d_in[8];
    const float* fc1w = (const float*)d_in[9];
    const float* fc1b = (const float*)d_in[10];
    const float* fc2w = (const float*)d_in[11];
    const float* fc2b = (const float*)d_in[12];
    float* out = (float*)d_out;

    const int n_nodes = in_sizes[2];
    const int n_edges = in_sizes[1] / 2;
    const int in_dim  = in_sizes[0] / n_nodes;   // 512
    const int Mpad    = (n_nodes + 63) & ~63;    // 20032
    const int nb      = (n_nodes + 255) / 256;   // scan chunks
    const int nG      = Mpad / 64;               // A-stripes (313)
    const int* src = ei;
    const int* dst = ei + n_edges;

    // workspace layout, 256B-aligned slices
    char* wsb = (char*)d_ws;
    size_t cur = 0;
    auto alloc = [&](size_t nbytes) { size_t o = cur; cur = (cur + nbytes + 255) & ~(size_t)255; return o; };
    size_t o_degi = alloc((size_t)n_nodes * 4);
    size_t o_off  = alloc((size_t)(n_nodes + 1) * 4);
    size_t o_cur  = alloc((size_t)n_nodes * 4);
    size_t o_part = alloc((size_t)nb * 4);
    size_t o_eidx = alloc((size_t)n_edges * 4);
    size_t o_w1   = alloc((size_t)NCOL * in_dim * 2);
    size_t o_w2   = alloc((size_t)NCOL * HID * 2);
    size_t o_xb   = alloc((size_t)Mpad * in_dim * 2);
    size_t o_hb   = alloc((size_t)Mpad * HID * 2);
    size_t o_y    = alloc((size_t)Mpad * NCOL * 2);
    size_t o_pool = alloc((size_t)16 * HID * 4 + 16 * 4);
    (void)ws_size;

    int*    degi    = (int*)(wsb + o_degi);
    int*    off     = (int*)(wsb + o_off);
    int*    cursor  = (int*)(wsb + o_cur);
    int*    partials= (int*)(wsb + o_part);
    int*    eidx    = (int*)(wsb + o_eidx);
    ushort* w1t     = (ushort*)(wsb + o_w1);
    ushort* w2t     = (ushort*)(wsb + o_w2);
    ushort* xb      = (ushort*)(wsb + o_xb);
    ushort* hb      = (ushort*)(wsb + o_hb);
    ushort* Y       = (ushort*)(wsb + o_y);
    float*  pooled  = (float*)(wsb + o_pool);
    float*  cnt     = pooled + 16 * HID;

    hipMemsetAsync(degi, 0, (size_t)n_nodes * 4, stream);
    hipMemsetAsync(pooled, 0, (size_t)(16 * HID + 16) * 4, stream);

    // ---- fused prep: cvt | packT W1 | packT W2 | degree histogram
    int n4 = n_nodes * in_dim / 4;
    int nb_cvt = (n4 + 255) / 256;
    int nb_w1  = (NCOL * in_dim + 255) / 256;
    int nb_w2  = (NCOL * HID + 255) / 256;
    int nb_deg = (n_edges + 255) / 256;
    prep_kernel<<<nb_cvt + nb_w1 + nb_w2 + nb_deg, 256, 0, stream>>>(
        x, xb, n4, W1n, W1s, w1t, in_dim, W2n, W2s, w2t, HID,
        dst, degi, n_edges, nb_cvt, nb_w1, nb_w2);

    // ---- CSR build: hierarchical scan -> fill
    psum_kernel<<<nb, 256, 0, stream>>>(degi, partials, n_nodes);
    pscan_kernel<<<1, 64, 0, stream>>>(partials, off, nb, n_nodes);
    scan2_kernel<<<nb, 256, 0, stream>>>(degi, partials, off, cursor, n_nodes);
    fill_kernel<<<(n_edges + 255) / 256, 256, 0, stream>>>(src, dst, cursor, eidx, n_edges);

    // XCD-grouped 1D gemm grid
    int gemm_blocks = 8 * 4 * ((nG + 7) / 8);
    int gather_blocks = (n_nodes + 3) / 4;

    // ---- layer 1
    gemm_mfma<<<gemm_blocks, 256, 0, stream>>>(xb, w1t, Y, in_dim, nG);
    gather_kernel<<<gather_blocks, 256, 0, stream>>>(Y, off, eidx, b1, hb, n_nodes);

    // ---- layer 2
    gemm_mfma<<<gemm_blocks, 256, 0, stream>>>(hb, w2t, Y, HID, nG);
    gather_kernel<<<gather_blocks, 256, 0, stream>>>(Y, off, eidx, b2, hb, n_nodes);

    // ---- pool + head
    pool_kernel<<<(n_nodes + 63) / 64, 256, 0, stream>>>(hb, batch, pooled, cnt, n_nodes);
    head_kernel<<<16, 128, 0, stream>>>(pooled, cnt, fc1w, fc1b, fc2w, fc2b, out);
}